// Round 3
// baseline (296.926 us; speedup 1.0000x reference)
//
#include <hip/hip_runtime.h>
#include <hip/hip_bf16.h>

typedef __attribute__((ext_vector_type(8))) short short8;   // 8 bf16 MFMA frag
typedef __attribute__((ext_vector_type(4))) float f32x4;

#define Bb 64
#define Cc 64
#define Tt 32
#define Nn 64
#define Kk 3
#define PITCH 72                // sX1 row pitch (write-free; read count tiny)
#define OUT_A_OFF 8388608L      // B*C*T*N floats of x_out, then verbatim A copy

__device__ __forceinline__ short f2bf(float f) {
    __hip_bfloat16 h = __float2bfloat16(f);
    return *reinterpret_cast<short*>(&h);
}

// Shared B-operand buffer sU: logical row-major [64 rows][64 cols] bf16 with a
// column-block XOR swizzle. addr(row,col) = row*64 + (col ^ (swz(row)<<3)),
// bijective per row (correctness independent of bank math).
//  - transposed scalar writes (row = 4*(tid&15)+i varies per lane): the varying
//    row bits enter col bits[5:3] -> 32 distinct bank-words/wave -> 2-way = free.
//  - b128 reads (row = 16*t+lr, col-block lq): all 32 banks hit uniformly,
//    structural 8-cycle minimum for 1KB/wave, no serialization.
#define SWZ(row) ((((row) >> 3) ^ (row)) & 7)
#define SADDR(row, col) (((row) << 6) + ((col) ^ (SWZ(row) << 3)))

// One block per (b,t), 256 threads = 4 waves. Grid 2048 = 256 CU x 8 blocks.
// step1: x1(64x64) = W @ x (bf16 MFMA, W frags direct from global/L2).
// per k: deg/rsqrt, S += (A_k + I) * dinv * dinv^T accumulated in registers.
// step3: out = x1 @ S (single MFMA pass; x1 is k-invariant so the k-sum moves
//        into S). Fused verbatim fp32 copy of A -> out[OUT_A_OFF..].
// NOTE: plain stores only. R2 measured __builtin_nontemporal_store doubling
// BOTH WRITE_SIZE (131->258 MB, broken write-combining) and FETCH_SIZE
// (66->130 MB, lost L3 retention of inputs). nt stores are banned here.
__global__ __launch_bounds__(256, 8) void ctg_kernel(
    const float* __restrict__ X,
    const float* __restrict__ A,
    const float* __restrict__ W,
    const float* __restrict__ bias,
    float* __restrict__ out)
{
    __shared__ __attribute__((aligned(16))) short sU [64 * 64];     // x^T (step1) then S (step3)
    __shared__ __attribute__((aligned(16))) short sX1[Cc * PITCH];  // x1[c][n], A-op for step3
    __shared__ __attribute__((aligned(16))) float sDv[Kk][Nn];      // per-k dinv

    const int tid  = threadIdx.x;
    const int b    = blockIdx.x >> 5;     // T = 32
    const int t    = blockIdx.x & 31;
    const int l    = tid & 63;
    const int w    = tid >> 6;            // wave id 0..3 -> output row stripe
    const int lr   = l & 15;              // MFMA: A-row / B-col / C-col
    const int lq   = l >> 4;              // MFMA quad
    const int m0   = 4 * (tid & 15);      // owned column block of A slab
    const int nrow = tid >> 4;            // owned row base (n = nrow + 16e)

    const long xbase  = (long)b * (Cc * Tt * Nn) + (long)t * Nn;
    const long Abase0 = (long)b * (Kk * Tt * Nn * Nn) + (long)t * (Nn * Nn);

    // ---- stage x^T into sU: rows = n, cols = cin (B-op: contiguous k along row) ----
    #pragma unroll
    for (int j = 0; j < 4; ++j) {
        int c  = nrow + 16 * j;           // channel
        f32x4 xv = *(const f32x4*)(X + xbase + (long)c * (Tt * Nn) + m0);
        #pragma unroll
        for (int i = 0; i < 4; ++i)
            sU[SADDR(m0 + i, c)] = f2bf(xv[i]);   // row = n = m0+i, col = c
    }

    // ---- W fragments direct from global (16KB, L2-resident across 2048 blocks) ----
    const float* wrow = W + (16 * w + lr) * Cc;
    f32x4 wv0 = *(const f32x4*)(wrow + 8 * lq);
    f32x4 wv1 = *(const f32x4*)(wrow + 8 * lq + 4);
    f32x4 wv2 = *(const f32x4*)(wrow + 32 + 8 * lq);
    f32x4 wv3 = *(const f32x4*)(wrow + 32 + 8 * lq + 4);
    f32x4 bv  = *(const f32x4*)(bias + 16 * w + 4 * lq);
    short8 aw0, aw1;
    #pragma unroll
    for (int i = 0; i < 4; ++i) {
        aw0[i]     = f2bf(wv0[i]);
        aw0[i + 4] = f2bf(wv1[i]);
        aw1[i]     = f2bf(wv2[i]);
        aw1[i + 4] = f2bf(wv3[i]);
    }

    __syncthreads();                                   // B0: x^T staged

    // ---- step 1: x1 = W @ x ----
    f32x4 acc1[4];
    #pragma unroll
    for (int nt = 0; nt < 4; ++nt) {
        const int row = 16 * nt + lr;                  // n
        const int sw  = SWZ(row);
        short8 b0 = *(const short8*)&sU[(row << 6) + ((lq ^ sw) << 3)];        // k = 8lq..+7
        short8 b1 = *(const short8*)&sU[(row << 6) + (((4 + lq) ^ sw) << 3)];  // k = 32+8lq..+7
        acc1[nt] = (f32x4){0.f, 0.f, 0.f, 0.f};
        acc1[nt] = __builtin_amdgcn_mfma_f32_16x16x32_bf16(aw0, b0, acc1[nt], 0, 0, 0);
        acc1[nt] = __builtin_amdgcn_mfma_f32_16x16x32_bf16(aw1, b1, acc1[nt], 0, 0, 0);
    }
    // x1 (+bias) -> sX1 (A-op layout). C/D: row = 4lq+r, col = lr.
    #pragma unroll
    for (int nt = 0; nt < 4; ++nt)
        #pragma unroll
        for (int r = 0; r < 4; ++r) {
            int c = 16 * w + 4 * lq + r;
            sX1[c * PITCH + 16 * nt + lr] = f2bf(acc1[nt][r] + bv[r]);
        }

    // ---- per k: load A, fused copy-out, degrees, accumulate S = sum_k A_norm_k ----
    float S[4][4];
    #pragma unroll
    for (int e = 0; e < 4; ++e)
        #pragma unroll
        for (int i = 0; i < 4; ++i) S[e][i] = 0.f;

    for (int k = 0; k < Kk; ++k) {
        const long Ab = Abase0 + (long)k * (Tt * Nn * Nn);
        f32x4 av[4];
        #pragma unroll
        for (int e = 0; e < 4; ++e)
            av[e] = *(const f32x4*)(A + Ab + 4 * (tid + 256 * e));
        // verbatim A copy (plain store: allocates in L2/L3 -> write-combines,
        // and preserves input retention in L3)
        #pragma unroll
        for (int e = 0; e < 4; ++e)
            *(f32x4*)(out + OUT_A_OFF + Ab + 4 * (tid + 256 * e)) = av[e];

        // element (tid,e,i) = A[n = nrow+16e][m = m0+i]; row-sum via 16-lane butterfly
        float dnv[4];
        #pragma unroll
        for (int e = 0; e < 4; ++e) {
            float q = av[e][0] + av[e][1] + av[e][2] + av[e][3];
            q += __shfl_xor(q, 1);
            q += __shfl_xor(q, 2);
            q += __shfl_xor(q, 4);
            q += __shfl_xor(q, 8);
            dnv[e] = rsqrtf(q + 1.0f);                 // deg of A+I
        }
        if ((tid & 15) == 0) {
            #pragma unroll
            for (int e = 0; e < 4; ++e) sDv[k][nrow + 16 * e] = dnv[e];
        }
        __syncthreads();                               // Bk: dinv[k] visible (1 barrier/k)

        f32x4 dm = *(const f32x4*)&sDv[k][m0];
        #pragma unroll
        for (int e = 0; e < 4; ++e) {
            const int n  = nrow + 16 * e;
            const float dn = dnv[e];
            #pragma unroll
            for (int i = 0; i < 4; ++i) {
                float v = av[e][i];
                if (m0 + i == n) v += 1.0f;            // renormalization trick: A + I
                S[e][i] += v * dn * dm[i];
            }
        }
    }

    // ---- stage S into sU: rows = m, cols = n (B-op for step3; overwrite of x^T
    //      is fenced: all x^T reads precede barrier Bk(k=0)) ----
    #pragma unroll
    for (int e = 0; e < 4; ++e) {
        int n = nrow + 16 * e;
        #pragma unroll
        for (int i = 0; i < 4; ++i)
            sU[SADDR(m0 + i, n)] = f2bf(S[e][i]);      // row = m = m0+i, col = n
    }
    __syncthreads();                                   // B4: S staged, sX1 published

    // ---- step 3: out = x1 @ S (single pass) ----
    const short8 a0 = *(const short8*)&sX1[(16 * w + lr) * PITCH + 8 * lq];
    const short8 a1 = *(const short8*)&sX1[(16 * w + lr) * PITCH + 32 + 8 * lq];
    f32x4 acc3[4];
    #pragma unroll
    for (int mt = 0; mt < 4; ++mt) {
        const int row = 16 * mt + lr;                  // m
        const int sw  = SWZ(row);
        short8 b0 = *(const short8*)&sU[(row << 6) + ((lq ^ sw) << 3)];        // n = 8lq..+7
        short8 b1 = *(const short8*)&sU[(row << 6) + (((4 + lq) ^ sw) << 3)];  // n = 32+8lq..+7
        acc3[mt] = (f32x4){0.f, 0.f, 0.f, 0.f};
        acc3[mt] = __builtin_amdgcn_mfma_f32_16x16x32_bf16(a0, b0, acc3[mt], 0, 0, 0);
        acc3[mt] = __builtin_amdgcn_mfma_f32_16x16x32_bf16(a1, b1, acc3[mt], 0, 0, 0);
    }

    // ---- store x_out fp32; C/D: row = c, col = m ----
    #pragma unroll
    for (int mt = 0; mt < 4; ++mt)
        #pragma unroll
        for (int r = 0; r < 4; ++r) {
            int c = 16 * w + 4 * lq + r;
            out[xbase + (long)c * (Tt * Nn) + 16 * mt + lr] = acc3[mt][r];
        }
}

extern "C" void kernel_launch(void* const* d_in, const int* in_sizes, int n_in,
                              void* d_out, int out_size, void* d_ws, size_t ws_size,
                              hipStream_t stream) {
    const float* X    = (const float*)d_in[0];
    const float* A    = (const float*)d_in[1];
    const float* W    = (const float*)d_in[2];
    const float* bias = (const float*)d_in[3];
    float* out = (float*)d_out;
    ctg_kernel<<<dim3(Bb * Tt), dim3(256), 0, stream>>>(X, A, W, bias, out);
}

// Round 4
// 236.590 us; speedup vs baseline: 1.2550x; 1.2550x over previous
//
#include <hip/hip_runtime.h>
#include <hip/hip_bf16.h>

typedef __attribute__((ext_vector_type(8))) short short8;   // 8 bf16 MFMA frag
typedef __attribute__((ext_vector_type(4))) float f32x4;

#define Bb 64
#define Cc 64
#define Tt 32
#define Nn 64
#define Kk 3
#define PITCH 72                // sX1 row pitch (write-free; read count tiny)
#define OUT_A_OFF 8388608L      // B*C*T*N floats of x_out, then verbatim A copy

__device__ __forceinline__ short f2bf(float f) {
    __hip_bfloat16 h = __float2bfloat16(f);
    return *reinterpret_cast<short*>(&h);
}

// Shared B-operand buffer sU: logical row-major [64 rows][64 cols] bf16 with a
// column-block XOR swizzle. addr(row,col) = row*64 + (col ^ (swz(row)<<3)),
// bijective per row. Transposed scalar writes: 2-way = free; b128 reads: all 32
// banks uniform (structural minimum). Verified R2/R3: conflicts 8.65M -> 1.11M.
#define SWZ(row) ((((row) >> 3) ^ (row)) & 7)
#define SADDR(row, col) (((row) << 6) + ((col) ^ (SWZ(row) << 3)))

// One block per (b,t), 256 threads = 4 waves, 4 blocks/CU (NOT 8: R2/R3 measured
// 8/CU doubling HBM traffic — 2048 concurrent tiles thrash L2/L3, evicting the
// harness's memset-dirty output lines before our overwrite (2x WRITE_SIZE) and
// evicting inputs before the next iteration re-reads them (2x FETCH_SIZE).
// R0 at 4/CU had fetch 66 MB / write 131 MB; R3 at 8/CU: 130/256).
//
// step1: x1(64x64) = W @ x (bf16 MFMA, W frags direct from global/L2).
// A phase: ALL 3 k-slabs hoisted to registers (12 f32x4 in flight, issued under
//          step1's MFMAs), fused verbatim copy-out, one degree barrier.
// step3:  out = x1 @ S with S = sum_k (A_k+I) d d^T accumulated in registers.
// Barriers: 3 total (x^T staged / sDv / S staged). sX1 is wave-private: wave w
// writes rows 16w..16w+15 and reads only those -> no barrier needed for it.
__global__ __launch_bounds__(256, 4) void ctg_kernel(
    const float* __restrict__ X,
    const float* __restrict__ A,
    const float* __restrict__ W,
    const float* __restrict__ bias,
    float* __restrict__ out)
{
    __shared__ __attribute__((aligned(16))) short sU [64 * 64];     // x^T (step1) then S (step3)
    __shared__ __attribute__((aligned(16))) short sX1[Cc * PITCH];  // x1[c][n], wave-private rows
    __shared__ __attribute__((aligned(16))) float sDv[Kk][Nn];      // per-k dinv

    const int tid  = threadIdx.x;
    const int b    = blockIdx.x >> 5;     // T = 32
    const int t    = blockIdx.x & 31;
    const int l    = tid & 63;
    const int w    = tid >> 6;            // wave id 0..3 -> output row stripe
    const int lr   = l & 15;              // MFMA: A-row / B-col / C-col
    const int lq   = l >> 4;              // MFMA quad
    const int m0   = 4 * (tid & 15);      // owned column block of A slab
    const int nrow = tid >> 4;            // owned row base (n = nrow + 16e)

    const long xbase  = (long)b * (Cc * Tt * Nn) + (long)t * Nn;
    const long Abase0 = (long)b * (Kk * Tt * Nn * Nn) + (long)t * (Nn * Nn);

    // ---- stage x^T into sU: rows = n, cols = cin (B-op: contiguous k along row) ----
    #pragma unroll
    for (int j = 0; j < 4; ++j) {
        int c  = nrow + 16 * j;           // channel
        f32x4 xv = *(const f32x4*)(X + xbase + (long)c * (Tt * Nn) + m0);
        #pragma unroll
        for (int i = 0; i < 4; ++i)
            sU[SADDR(m0 + i, c)] = f2bf(xv[i]);   // row = n = m0+i, col = c
    }

    // ---- W fragments direct from global (16KB, L2-resident across blocks) ----
    const float* wrow = W + (16 * w + lr) * Cc;
    f32x4 wv0 = *(const f32x4*)(wrow + 8 * lq);
    f32x4 wv1 = *(const f32x4*)(wrow + 8 * lq + 4);
    f32x4 wv2 = *(const f32x4*)(wrow + 32 + 8 * lq);
    f32x4 wv3 = *(const f32x4*)(wrow + 32 + 8 * lq + 4);
    f32x4 bv  = *(const f32x4*)(bias + 16 * w + 4 * lq);
    short8 aw0, aw1;
    #pragma unroll
    for (int i = 0; i < 4; ++i) {
        aw0[i]     = f2bf(wv0[i]);
        aw0[i + 4] = f2bf(wv1[i]);
        aw1[i]     = f2bf(wv2[i]);
        aw1[i + 4] = f2bf(wv3[i]);
    }

    __syncthreads();                                   // B0: x^T staged

    // ---- issue ALL A loads now (12 f32x4/thread in flight); latency hides
    //      under the step-1 MFMA sequence below ----
    f32x4 av[Kk][4];
    #pragma unroll
    for (int k = 0; k < Kk; ++k) {
        const long Ab = Abase0 + (long)k * (Tt * Nn * Nn);
        #pragma unroll
        for (int e = 0; e < 4; ++e)
            av[k][e] = *(const f32x4*)(A + Ab + 4 * (tid + 256 * e));
    }

    // ---- step 1: x1 = W @ x ----
    f32x4 acc1[4];
    #pragma unroll
    for (int nt = 0; nt < 4; ++nt) {
        const int row = 16 * nt + lr;                  // n
        const int sw  = SWZ(row);
        short8 b0 = *(const short8*)&sU[(row << 6) + ((lq ^ sw) << 3)];        // k = 8lq..+7
        short8 b1 = *(const short8*)&sU[(row << 6) + (((4 + lq) ^ sw) << 3)];  // k = 32+8lq..+7
        acc1[nt] = (f32x4){0.f, 0.f, 0.f, 0.f};
        acc1[nt] = __builtin_amdgcn_mfma_f32_16x16x32_bf16(aw0, b0, acc1[nt], 0, 0, 0);
        acc1[nt] = __builtin_amdgcn_mfma_f32_16x16x32_bf16(aw1, b1, acc1[nt], 0, 0, 0);
    }
    // x1 (+bias) -> sX1 (A-op layout, wave-private rows; no barrier needed)
    #pragma unroll
    for (int nt = 0; nt < 4; ++nt)
        #pragma unroll
        for (int r = 0; r < 4; ++r) {
            int c = 16 * w + 4 * lq + r;
            sX1[c * PITCH + 16 * nt + lr] = f2bf(acc1[nt][r] + bv[r]);
        }

    // ---- verbatim A copy-out (loads have completed under step1) ----
    #pragma unroll
    for (int k = 0; k < Kk; ++k) {
        const long Ab = Abase0 + (long)k * (Tt * Nn * Nn);
        #pragma unroll
        for (int e = 0; e < 4; ++e)
            *(f32x4*)(out + OUT_A_OFF + Ab + 4 * (tid + 256 * e)) = av[k][e];
    }

    // ---- degrees for all 3 k: element (tid,e,i) = A[n = nrow+16e][m = m0+i] ----
    float dnv[Kk][4];
    #pragma unroll
    for (int k = 0; k < Kk; ++k)
        #pragma unroll
        for (int e = 0; e < 4; ++e) {
            float q = av[k][e][0] + av[k][e][1] + av[k][e][2] + av[k][e][3];
            q += __shfl_xor(q, 1);
            q += __shfl_xor(q, 2);
            q += __shfl_xor(q, 4);
            q += __shfl_xor(q, 8);
            dnv[k][e] = rsqrtf(q + 1.0f);              // deg of A+I
        }
    if ((tid & 15) == 0)
        #pragma unroll
        for (int k = 0; k < Kk; ++k)
            #pragma unroll
            for (int e = 0; e < 4; ++e) sDv[k][nrow + 16 * e] = dnv[k][e];
    __syncthreads();                                   // B1: all dinv visible

    // ---- normalize + accumulate S = sum_k A_norm_k in registers ----
    float S[4][4];
    #pragma unroll
    for (int e = 0; e < 4; ++e)
        #pragma unroll
        for (int i = 0; i < 4; ++i) S[e][i] = 0.f;
    #pragma unroll
    for (int k = 0; k < Kk; ++k) {
        f32x4 dm = *(const f32x4*)&sDv[k][m0];
        #pragma unroll
        for (int e = 0; e < 4; ++e) {
            const int n  = nrow + 16 * e;
            const float dn = dnv[k][e];
            #pragma unroll
            for (int i = 0; i < 4; ++i) {
                float v = av[k][e][i];
                if (m0 + i == n) v += 1.0f;            // renormalization trick: A + I
                S[e][i] += v * dn * dm[i];
            }
        }
    }

    // ---- stage S into sU: rows = m, cols = n (x^T overwrite fenced by B1) ----
    #pragma unroll
    for (int e = 0; e < 4; ++e) {
        int n = nrow + 16 * e;
        #pragma unroll
        for (int i = 0; i < 4; ++i)
            sU[SADDR(m0 + i, n)] = f2bf(S[e][i]);      // row = m = m0+i, col = n
    }
    __syncthreads();                                   // B2: S staged

    // ---- step 3: out = x1 @ S (single pass) ----
    const short8 a0 = *(const short8*)&sX1[(16 * w + lr) * PITCH + 8 * lq];
    const short8 a1 = *(const short8*)&sX1[(16 * w + lr) * PITCH + 32 + 8 * lq];
    f32x4 acc3[4];
    #pragma unroll
    for (int mt = 0; mt < 4; ++mt) {
        const int row = 16 * mt + lr;                  // m
        const int sw  = SWZ(row);
        short8 b0 = *(const short8*)&sU[(row << 6) + ((lq ^ sw) << 3)];        // n = 8lq..+7
        short8 b1 = *(const short8*)&sU[(row << 6) + (((4 + lq) ^ sw) << 3)];  // n = 32+8lq..+7
        acc3[mt] = (f32x4){0.f, 0.f, 0.f, 0.f};
        acc3[mt] = __builtin_amdgcn_mfma_f32_16x16x32_bf16(a0, b0, acc3[mt], 0, 0, 0);
        acc3[mt] = __builtin_amdgcn_mfma_f32_16x16x32_bf16(a1, b1, acc3[mt], 0, 0, 0);
    }

    // ---- store x_out fp32; C/D: row = c, col = m ----
    #pragma unroll
    for (int mt = 0; mt < 4; ++mt)
        #pragma unroll
        for (int r = 0; r < 4; ++r) {
            int c = 16 * w + 4 * lq + r;
            out[xbase + (long)c * (Tt * Nn) + 16 * mt + lr] = acc3[mt][r];
        }
}

extern "C" void kernel_launch(void* const* d_in, const int* in_sizes, int n_in,
                              void* d_out, int out_size, void* d_ws, size_t ws_size,
                              hipStream_t stream) {
    const float* X    = (const float*)d_in[0];
    const float* A    = (const float*)d_in[1];
    const float* W    = (const float*)d_in[2];
    const float* bias = (const float*)d_in[3];
    float* out = (float*)d_out;
    ctg_kernel<<<dim3(Bb * Tt), dim3(256), 0, stream>>>(X, A, W, bias, out);
}